// Round 2
// baseline (451.971 us; speedup 1.0000x reference)
//
#include <hip/hip_runtime.h>

// 5-level 3D Haar wavedec (db1, mode=zero, even sizes -> no padding).
// Input [4,8,128,128,128] fp32.
// V2b: each thread owns FOUR half-res voxels along W (one 16B vector per subband).
// Reads its 2x2x8 input brick as 8x 16B loads (16B/lane, coalesced), does the
// separable butterfly per output voxel, writes aaa + 7 detail subbands as 16B
// stores. Input + detail streams use non-temporal hints (touched exactly once);
// aaa stays cached for the next level's read.
// aaa chain ping-pongs through d_ws; level-5 aaa = Yl goes to d_out[0].

#define C3 0.3535533905932738f  // (1/sqrt(2))^3

// native vector type (NOT HIP float4 class) so nontemporal builtins accept it
typedef float f4 __attribute__((ext_vector_type(4)));

__global__ __launch_bounds__(256) void haar3_lvl(
    const float* __restrict__ in, float* __restrict__ out_a,
    float* __restrict__ out_d, long det_sz, int log2n, long nq)
{
    const long q = (long)blockIdx.x * 256 + threadIdx.x;
    if (q >= nq) return;
    const int n = 1 << log2n;
    const int wg = (int)(q & ((n >> 2) - 1));            // W group of 4 out-voxels
    const int hy = (int)((q >> (log2n - 2)) & (n - 1));
    const int dz = (int)((q >> (2 * log2n - 2)) & (n - 1));
    const long b = q >> (3 * log2n - 2);
    const long n2   = 2 * (long)n;
    const long rowD = n2 * n2;  // stride between D slices of the input
    const long base = ((b * n2 + 2 * dz) * n2 + 2 * hy) * n2 + 8 * (long)wg;

    // rows: r[0]=(dd0,dh0) r[1]=(dd0,dh1) r[2]=(dd1,dh0) r[3]=(dd1,dh1)
    __attribute__((aligned(16))) float r[4][8];
    const f4* p00 = (const f4*)(in + base);
    const f4* p01 = (const f4*)(in + base + n2);
    const f4* p10 = (const f4*)(in + base + rowD);
    const f4* p11 = (const f4*)(in + base + rowD + n2);
    *(f4*)&r[0][0] = __builtin_nontemporal_load(p00);
    *(f4*)&r[0][4] = __builtin_nontemporal_load(p00 + 1);
    *(f4*)&r[1][0] = __builtin_nontemporal_load(p01);
    *(f4*)&r[1][4] = __builtin_nontemporal_load(p01 + 1);
    *(f4*)&r[2][0] = __builtin_nontemporal_load(p10);
    *(f4*)&r[2][4] = __builtin_nontemporal_load(p10 + 1);
    *(f4*)&r[3][0] = __builtin_nontemporal_load(p11);
    *(f4*)&r[3][4] = __builtin_nontemporal_load(p11 + 1);

    // o[s][j]: s = subband (0=aaa, then aad,ada,add,daa,dad,dda,ddd), j = voxel
    __attribute__((aligned(16))) float o[8][4];
#pragma unroll
    for (int j = 0; j < 4; ++j) {
        // W butterfly (scale folded into final C3)
        const float aw0 = r[0][2*j] + r[0][2*j+1], dw0 = r[0][2*j] - r[0][2*j+1];
        const float aw1 = r[1][2*j] + r[1][2*j+1], dw1 = r[1][2*j] - r[1][2*j+1];
        const float aw2 = r[2][2*j] + r[2][2*j+1], dw2 = r[2][2*j] - r[2][2*j+1];
        const float aw3 = r[3][2*j] + r[3][2*j+1], dw3 = r[3][2*j] - r[3][2*j+1];
        // H butterfly within each D slice
        const float aa0 = aw0 + aw1, da0 = aw0 - aw1, ad0 = dw0 + dw1, dd0 = dw0 - dw1;
        const float aa1 = aw2 + aw3, da1 = aw2 - aw3, ad1 = dw2 + dw3, dd1 = dw2 - dw3;
        // D butterfly -> 8 subbands; detail order matches KEYS (D,H,W letters):
        o[0][j] = (aa0 + aa1) * C3;  // aaa
        o[1][j] = (ad0 + ad1) * C3;  // aad
        o[2][j] = (da0 + da1) * C3;  // ada
        o[3][j] = (dd0 + dd1) * C3;  // add
        o[4][j] = (aa0 - aa1) * C3;  // daa
        o[5][j] = (ad0 - ad1) * C3;  // dad
        o[6][j] = (da0 - da1) * C3;  // dda
        o[7][j] = (dd0 - dd1) * C3;  // ddd
    }

    const long t4 = q << 2;  // linear output index of voxel 0
    *(f4*)(out_a + t4) = *(const f4*)&o[0][0];  // aaa: plain store, next level re-reads it
#pragma unroll
    for (int s = 0; s < 7; ++s)
        __builtin_nontemporal_store(*(const f4*)&o[s + 1][0],
                                    (f4*)(out_d + (long)s * det_sz + t4));
}

extern "C" void kernel_launch(void* const* d_in, const int* in_sizes, int n_in,
                              void* d_out, int out_size, void* d_ws, size_t ws_size,
                              hipStream_t stream) {
    const float* x = (const float*)d_in[0];
    float* out  = (float*)d_out;
    float* buf0 = (float*)d_ws;              // 32*64^3 = 8,388,608 floats
    float* buf1 = buf0 + 8388608;            // 32*32^3 = 1,048,576 floats
    // ws usage: 9,437,184 floats = 36 MB

    // d_out layout (flat, fp32): Yl[2048] | L5 det 7x2048 | L4 det 7x16384 |
    // L3 det 7x131072 | L2 det 7x1048576 | L1 det 7x8388608
    struct Lv { const float* in; float* oa; float* od; int log2n; };
    const Lv lv[5] = {
        { x,    buf0, out + 8388608, 6 },  // L1: 128^3 -> 64^3
        { buf0, buf1, out + 1048576, 5 },  // L2: 64^3  -> 32^3
        { buf1, buf0, out + 131072,  4 },  // L3: 32^3  -> 16^3
        { buf0, buf1, out + 16384,   3 },  // L4: 16^3  -> 8^3
        { buf1, out,  out + 2048,    2 },  // L5: 8^3   -> 4^3, aaa -> Yl at offset 0
    };
    const long BC = 32;  // batch * channels
    for (int i = 0; i < 5; ++i) {
        const long total = BC << (3 * lv[i].log2n);   // output voxels this level
        const long nq    = total >> 2;                // threads: 4 voxels each
        const int blocks = (int)((nq + 255) / 256);
        haar3_lvl<<<blocks, 256, 0, stream>>>(lv[i].in, lv[i].oa, lv[i].od,
                                              total, lv[i].log2n, nq);
    }
}